// Round 3
// baseline (150.779 us; speedup 1.0000x reference)
//
#include <hip/hip_runtime.h>

// Shape fixed by setup_inputs: B=4, L=4096, D=1024 (D re-derived at launch).
#define BB   4
#define LL   4096
#define KCH  16                  // boundaries per chunk
#define CMAX (LL / KCH)          // 256 worst-case chunks (all tokens boundaries)
#define TT   16                  // tokens per k_out block
#define EPSP 1e-4f

__device__ __forceinline__ void ema4(float4& h, float p, const float4 x) {
    h.x = fmaf(p, x.x - h.x, h.x);
    h.y = fmaf(p, x.y - h.y, h.y);
    h.z = fmaf(p, x.z - h.z, h.z);
    h.w = fmaf(p, x.w - h.w, h.w);
}
__device__ __forceinline__ float4 fma4s(float a, const float4 x, const float4 y) {
    float4 r;
    r.x = fmaf(a, x.x, y.x);
    r.y = fmaf(a, x.y, y.y);
    r.z = fmaf(a, x.z, y.z);
    r.w = fmaf(a, x.w, y.w);
    return r;
}

// ------------- kernel 1: compaction -> pk, nb, plug_back idx ----------------
// grid = B, block = 256; thread owns LL/256 = 16 contiguous tokens.
__global__ void k_setup(const float* __restrict__ bp, const int* __restrict__ mask,
                        int* __restrict__ nb, float* __restrict__ pk,
                        int* __restrict__ idxg) {
    const int b   = blockIdx.x;
    const int tid = threadIdx.x;
    const int PER = LL / 256;
    const int base = tid * PER;

    int m[PER];
    int cnt = 0;
    for (int i = 0; i < PER; ++i) { m[i] = mask[b * LL + base + i]; cnt += (m[i] != 0); }

    __shared__ int s[256];
    __shared__ int s_idx[LL];          // 16 KiB: stage idx for coalesced write
    s[tid] = cnt;
    __syncthreads();
    for (int off = 1; off < 256; off <<= 1) {      // Hillis-Steele inclusive scan
        int v = (tid >= off) ? s[tid - off] : 0;
        __syncthreads();
        s[tid] += v;
        __syncthreads();
    }
    int k = s[tid] - cnt;              // exclusive prefix = rank of first owned boundary
    const int total = s[255];

    int cc = k;
    for (int i = 0; i < PER; ++i) {
        int t = base + i;
        if (m[i] != 0) {
            float p = bp[(size_t)(b * LL + t) * 2 + 1];
            p = fminf(fmaxf(p, EPSP), 1.0f - EPSP);
            pk[b * LL + cc] = p;
            ++cc;
        }
        s_idx[t] = cc - 1;             // plug_back_idx = cumsum(mask)-1
    }
    __syncthreads();
    for (int j = 0; j < PER; ++j)      // coalesced idx write
        idxg[b * LL + j * 256 + tid] = s_idx[j * 256 + tid];
    if (tid == 0) nb[b] = total;
}

// ------------- kernel 2: per-chunk local states + decay prefixes ------------
// grid = (CMAX, B), block = 256 (one float4 of D per thread).
__global__ __launch_bounds__(256) void
k_chunk(const float4* __restrict__ X4, const int* __restrict__ nb,
        const float* __restrict__ pk, float4* __restrict__ Hl4,
        float* __restrict__ Dkg, float* __restrict__ Adec, int D4) {
    const int c = blockIdx.x, b = blockIdx.y;
    const int n  = nb[b];
    const int k0 = c * KCH;
    if (k0 >= n) return;
    const int nk = (k0 + KCH < n) ? KCH : (n - k0);
    const int tid = threadIdx.x;

    __shared__ float sp[KCH];
    if (tid < nk) sp[tid] = pk[b * LL + k0 + tid];
    __syncthreads();

    if (tid < nk) {                    // within-chunk cumulative decay products
        float Dd = 1.0f;
        for (int j = 0; j <= tid; ++j) Dd *= (1.0f - sp[j]);
        Dkg[b * LL + k0 + tid] = Dd;
        if (tid == nk - 1) Adec[b * CMAX + c] = Dd;   // full-chunk product
    }

    const float4* xp = X4 + (size_t)(b * LL + k0) * D4 + tid;
    float4*       hp = Hl4 + (size_t)(b * LL + k0) * D4 + tid;
    float4 h = {0.f, 0.f, 0.f, 0.f};
    for (int k = 0; k < nk; ++k) {
        ema4(h, sp[k], xp[(size_t)k * D4]);
        hp[(size_t)k * D4] = h;        // local state at boundary k (H_in = 0)
    }
}

// ------------- kernel 3: exclusive scan over chunks -> Hin[b,c,:] -----------
// grid = (B, 4), block = 64; each block owns 64 float4 channels.
__global__ __launch_bounds__(64) void
k_prefix(const float4* __restrict__ Hl4, const float* __restrict__ Adec,
         const int* __restrict__ nb, float4* __restrict__ Hin4, int D4) {
    const int b = blockIdx.x;
    const int d = blockIdx.y * 64 + threadIdx.x;
    const int n = nb[b];
    const int C = (n + KCH - 1) / KCH;

    float4 H = {0.f, 0.f, 0.f, 0.f};
    for (int c = 0; c < C; ++c) {
        Hin4[(size_t)(b * CMAX + c) * D4 + d] = H;            // exclusive
        const int klast = ((c + 1) * KCH < n ? (c + 1) * KCH : n) - 1;
        float4 u = Hl4[(size_t)(b * LL + klast) * D4 + d];
        float  A = Adec[b * CMAX + c];
        H = fma4s(A, H, u);
    }
}

// ------------- kernel 4: pure gather + affine fix, fully parallel -----------
// grid = (LL/TT, B), block = 256. out[b,t,:] = Hlocal[k] + Dk * Hin[k/KCH]
__global__ __launch_bounds__(256) void
k_out(const float4* __restrict__ Hl4, const float4* __restrict__ Hin4,
      const float* __restrict__ Dkg, const int* __restrict__ idxg,
      float4* __restrict__ out4, int D4) {
    const int b  = blockIdx.y;
    const int t0 = blockIdx.x * TT;
    const int tid = threadIdx.x;

    __shared__ int sk[TT];
    if (tid < TT) sk[tid] = idxg[b * LL + t0 + tid];
    __syncthreads();

    float4* op = out4 + (size_t)(b * LL + t0) * D4 + tid;
    int kprev = -1;
    float4 v = {0.f, 0.f, 0.f, 0.f};
    for (int t = 0; t < TT; ++t) {
        const int k = sk[t];                       // block-uniform
        if (k != kprev) {
            const int c = k / KCH;
            const float  Dv = Dkg[b * LL + k];
            const float4 hl = Hl4[(size_t)(b * LL + k) * D4 + tid];
            const float4 hi = Hin4[(size_t)(b * CMAX + c) * D4 + tid];
            v = fma4s(Dv, hi, hl);
            kprev = k;
        }
        op[(size_t)t * D4] = v;                    // 16 B/lane, coalesced
    }
}

extern "C" void kernel_launch(void* const* d_in, const int* in_sizes, int n_in,
                              void* d_out, int out_size, void* d_ws, size_t ws_size,
                              hipStream_t stream) {
    const float* X    = (const float*)d_in[0];   // hidden_states (B,L,D) f32
    const float* bp   = (const float*)d_in[1];   // boundary_prob (B,L,2) f32
    const int*   mask = (const int*)d_in[2];     // boundary_mask (B,L)
    float*       out  = (float*)d_out;           // (B,L,D) f32

    const int D  = in_sizes[0] / in_sizes[2];    // 1024
    const int D4 = D / 4;

    // workspace carve (16B-aligned; worst-case ~68.3 MiB of the 256 MiB ws)
    char* w = (char*)d_ws;
    int*   nb   = (int*)w;   w += 256;
    float* pk   = (float*)w; w += sizeof(float) * BB * LL;          // 64 KiB
    int*   idxg = (int*)w;   w += sizeof(int)   * BB * LL;          // 64 KiB
    float* Dkg  = (float*)w; w += sizeof(float) * BB * LL;          // 64 KiB
    float* Adec = (float*)w; w += sizeof(float) * BB * CMAX;        // 4 KiB
    float* Hin  = (float*)w; w += sizeof(float) * BB * CMAX * D;    // 4 MiB
    float* Hl   = (float*)w;                                        // worst 64 MiB

    k_setup<<<BB, 256, 0, stream>>>(bp, mask, nb, pk, idxg);
    k_chunk<<<dim3(CMAX, BB), 256, 0, stream>>>((const float4*)X, nb, pk,
                                                (float4*)Hl, Dkg, Adec, D4);
    k_prefix<<<dim3(BB, 4), 64, 0, stream>>>((const float4*)Hl, Adec, nb,
                                             (float4*)Hin, D4);
    k_out<<<dim3(LL / TT, BB), 256, 0, stream>>>((const float4*)Hl, (const float4*)Hin,
                                                 Dkg, idxg, (float4*)out, D4);
}

// Round 6
// 138.543 us; speedup vs baseline: 1.0883x; 1.0883x over previous
//
#include <hip/hip_runtime.h>

// Shape fixed by setup_inputs: B=4, L=4096, D=1024 (D re-derived at launch).
// Correct semantics: scan index k uses p from the k-th BOUNDARY token (compacted pk)
// but X from row k in ORIGINAL order (dense prefix 0..nb-1). Output gathers h at
// idx[t] = cumsum(mask)-1.
#define BB   4
#define LL   4096
#define CHK  32                  // scan positions per chunk (k_part)
#define NCK  (LL / CHK)          // 128 worst-case chunks
#define TT   32                  // tokens per k_out block
#define EPSP 1e-4f

typedef float v4f __attribute__((ext_vector_type(4)));

__device__ __forceinline__ void ema4(v4f& h, float p, const v4f x) {
    h.x = fmaf(p, x.x - h.x, h.x);
    h.y = fmaf(p, x.y - h.y, h.y);
    h.z = fmaf(p, x.z - h.z, h.z);
    h.w = fmaf(p, x.w - h.w, h.w);
}
__device__ __forceinline__ v4f fma4s(float a, const v4f x, const v4f y) {
    v4f r;
    r.x = fmaf(a, x.x, y.x);
    r.y = fmaf(a, x.y, y.y);
    r.z = fmaf(a, x.z, y.z);
    r.w = fmaf(a, x.w, y.w);
    return r;
}

// ------------- kernel 1: compaction -> pk, nb, plug_back idx ----------------
// grid = B, block = 256; thread owns LL/256 = 16 contiguous tokens.
__global__ void k_setup(const float* __restrict__ bp, const int* __restrict__ mask,
                        int* __restrict__ nb, float* __restrict__ pk,
                        int* __restrict__ idxg) {
    const int b   = blockIdx.x;
    const int tid = threadIdx.x;
    const int PER = LL / 256;
    const int base = tid * PER;

    int m[PER];
    int cnt = 0;
    for (int i = 0; i < PER; ++i) { m[i] = mask[b * LL + base + i]; cnt += (m[i] != 0); }

    __shared__ int s[256];
    __shared__ int s_idx[LL];          // 16 KiB staging for coalesced idx write
    s[tid] = cnt;
    __syncthreads();
    for (int off = 1; off < 256; off <<= 1) {      // Hillis-Steele inclusive scan
        int v = (tid >= off) ? s[tid - off] : 0;
        __syncthreads();
        s[tid] += v;
        __syncthreads();
    }
    int k = s[tid] - cnt;              // exclusive prefix
    const int total = s[255];

    int cc = k;
    for (int i = 0; i < PER; ++i) {
        int t = base + i;
        if (m[i] != 0) {
            float p = bp[(size_t)(b * LL + t) * 2 + 1];
            p = fminf(fmaxf(p, EPSP), 1.0f - EPSP);
            pk[b * LL + cc] = p;
            ++cc;
        }
        s_idx[t] = cc - 1;             // plug_back_idx = cumsum(mask)-1
    }
    __syncthreads();
    for (int j = 0; j < PER; ++j)
        idxg[b * LL + j * 256 + tid] = s_idx[j * 256 + tid];
    if (tid == 0) nb[b] = total;
}

// ------------- kernel 2: per-chunk partials U[b,c,:], Adec[b,c] -------------
// grid = (NCK, B), block = 256 (one v4f of D per thread). X rows read densely.
__global__ __launch_bounds__(256) void
k_part(const v4f* __restrict__ X4, const int* __restrict__ nb,
       const float* __restrict__ pk, v4f* __restrict__ U4,
       float* __restrict__ Adec, int D4) {
    const int c = blockIdx.x, b = blockIdx.y;
    const int n  = nb[b];
    const int k0 = c * CHK;
    if (k0 >= n) return;
    const int nk = (k0 + CHK < n) ? CHK : (n - k0);
    const int tid = threadIdx.x;

    __shared__ float sp[CHK];
    if (tid < nk) sp[tid] = pk[b * LL + k0 + tid];
    __syncthreads();

    const v4f* xp = X4 + (size_t)(b * LL + k0) * D4 + tid;
    v4f h = {0.f, 0.f, 0.f, 0.f};
    float A = 1.0f;
    for (int k = 0; k < nk; ++k) {
        const float p = sp[k];
        ema4(h, p, xp[(size_t)k * D4]);
        A *= (1.0f - p);
    }
    U4[(size_t)(b * NCK + c) * D4 + tid] = h;
    if (tid == 0) Adec[b * NCK + c] = A;
}

// ------------- kernel 3: token-parallel fixup + short redo + NT stores ------
// grid = (LL/TT, B), block = 256. Each block stores exactly TT rows (128 KiB).
__global__ __launch_bounds__(256) void
k_out(const v4f* __restrict__ X4, const float* __restrict__ pk,
      const int* __restrict__ idxg, const v4f* __restrict__ U4,
      const float* __restrict__ Adec, v4f* __restrict__ out4, int D4) {
    const int b  = blockIdx.y;
    const int t0 = blockIdx.x * TT;
    const int tid = threadIdx.x;

    __shared__ int   sk[TT];
    __shared__ float sA[NCK];
    __shared__ float sp[CHK + TT];
    if (tid < TT)  sk[tid] = idxg[b * LL + t0 + tid];
    if (tid < NCK) sA[tid] = Adec[b * NCK + tid];
    __syncthreads();

    const int k_lo   = sk[0];
    const int k_hi   = sk[TT - 1];          // block-uniform, k range width <= CHK+TT
    const int c_lo   = k_lo / CHK;
    const int kstart = c_lo * CHK;
    const int klen   = k_hi - kstart + 1;
    if (tid < klen) sp[tid] = pk[b * LL + kstart + tid];
    __syncthreads();

    // incoming state at chunk c_lo: redundant per-block affine recurrence (L2 loads)
    v4f H = {0.f, 0.f, 0.f, 0.f};
    const v4f* up = U4 + (size_t)b * NCK * D4 + tid;
    for (int cc = 0; cc < c_lo; ++cc)
        H = fma4s(sA[cc], H, up[(size_t)cc * D4]);

    // short scan redo over [kstart, k_hi]; store each owned token as k passes it
    const v4f* xp = X4 + (size_t)b * LL * D4 + tid;
    v4f*       op = out4 + (size_t)(b * LL + t0) * D4 + tid;
    v4f h = H;
    int t = 0;
    for (int k = kstart; k <= k_hi; ++k) {
        ema4(h, sp[k - kstart], xp[(size_t)k * D4]);
        while (t < TT && sk[t] == k) {
            __builtin_nontemporal_store(h, &op[(size_t)t * D4]);
            ++t;
        }
    }
}

extern "C" void kernel_launch(void* const* d_in, const int* in_sizes, int n_in,
                              void* d_out, int out_size, void* d_ws, size_t ws_size,
                              hipStream_t stream) {
    const float* X    = (const float*)d_in[0];   // hidden_states (B,L,D) f32
    const float* bp   = (const float*)d_in[1];   // boundary_prob (B,L,2) f32
    const int*   mask = (const int*)d_in[2];     // boundary_mask (B,L)
    float*       out  = (float*)d_out;           // (B,L,D) f32

    const int D  = in_sizes[0] / in_sizes[2];    // 1024
    const int D4 = D / 4;

    // workspace carve (16B-aligned; ~2.2 MiB total)
    char* w = (char*)d_ws;
    int*   nb   = (int*)w;   w += 256;
    float* pk   = (float*)w; w += sizeof(float) * BB * LL;        // 64 KiB
    int*   idxg = (int*)w;   w += sizeof(int)   * BB * LL;        // 64 KiB
    float* Adec = (float*)w; w += sizeof(float) * BB * NCK;       // 2 KiB
    w = (char*)(((uintptr_t)w + 15) & ~(uintptr_t)15);
    float* U    = (float*)w;                                      // BB*NCK*D = 2 MiB

    k_setup<<<BB, 256, 0, stream>>>(bp, mask, nb, pk, idxg);
    k_part<<<dim3(NCK, BB), 256, 0, stream>>>((const v4f*)X, nb, pk,
                                              (v4f*)U, Adec, D4);
    k_out<<<dim3(LL / TT, BB), 256, 0, stream>>>((const v4f*)X, pk, idxg,
                                                 (const v4f*)U, Adec,
                                                 (v4f*)out, D4);
}